// Round 2
// baseline (1018.102 us; speedup 1.0000x reference)
//
#include <hip/hip_runtime.h>
#include <cstdint>
#include <cstddef>

// ---------- types ----------
typedef __bf16  bf16x8f __attribute__((ext_vector_type(8)));      // MFMA A/B operand (4 VGPRs)
typedef unsigned short u16x8 __attribute__((ext_vector_type(8))); // storage view of 8 bf16
typedef float   f32x4  __attribute__((ext_vector_type(4)));       // MFMA C/D operand

__device__ __forceinline__ float bf2f(unsigned short s) {
    union { uint32_t u; float f; } c; c.u = ((uint32_t)s) << 16; return c.f;
}
__device__ __forceinline__ unsigned short f2bf(float f) {
    union { float f; uint32_t u; } c; c.f = f;
    uint32_t u = c.u;
    return (unsigned short)((u + 0x7fffu + ((u >> 16) & 1u)) >> 16);  // RNE
}

// ---------- kernel 0: detect mask storage layout ----------
// Probes first 4096 bytes of the mask buffer.
//   byte value > 1 anywhere            -> word layout (float32; nonzero-word test works)
//   else nonzero byte at k%4 != 0      -> uint8 (numpy bool) layout
//   else                               -> int32 layout (bytes of 1 = [1,0,0,0])
// flag = 1 -> uint8 path; flag = 0 -> 32-bit word path (int32 OR float32, both
// handled by "word != 0" truthiness).
__global__ __launch_bounds__(256)
void detect_mask(const unsigned char* __restrict__ m, int* __restrict__ flag) {
    __shared__ int s_gt1, s_off;
    if (threadIdx.x == 0) { s_gt1 = 0; s_off = 0; }
    __syncthreads();
    int gt1 = 0, off = 0;
    for (int k = threadIdx.x; k < 4096; k += 256) {
        unsigned char b = m[k];
        if (b > 1) gt1 = 1;
        if ((k & 3) && b) off = 1;
    }
    if (gt1) atomicOr(&s_gt1, 1);
    if (off) atomicOr(&s_off, 1);
    __syncthreads();
    if (threadIdx.x == 0) *flag = (!s_gt1 && s_off) ? 1 : 0;
}

// ---------- kernel 1: cast x fp32 -> bf16 ----------
__global__ __launch_bounds__(256)
void cast_f32_bf16(const float* __restrict__ in, unsigned short* __restrict__ out, int n) {
    int tid = blockIdx.x * blockDim.x + threadIdx.x;
    int stride = gridDim.x * blockDim.x;
    for (int e = tid * 4; e < n; e += stride * 4) {
        float4 v = *(const float4*)(in + e);
        ushort4 o;
        o.x = f2bf(v.x); o.y = f2bf(v.y); o.z = f2bf(v.z); o.w = f2bf(v.w);
        *(ushort4*)(out + e) = o;
    }
}

// ---------- kernel 2: masked weight -> bf16 (mask layout per flag) ----------
__global__ __launch_bounds__(256)
void mask_cast(const float* __restrict__ w, const void* __restrict__ mv,
               const int* __restrict__ flag, unsigned short* __restrict__ out, int n) {
    const bool u8 = (*flag != 0);   // uniform branch
    int tid = blockIdx.x * blockDim.x + threadIdx.x;
    int stride = gridDim.x * blockDim.x;
    for (int e = tid * 4; e < n; e += stride * 4) {
        float4 v = *(const float4*)(w + e);
        int m0, m1, m2, m3;
        if (u8) {
            uchar4 mm = *(const uchar4*)((const unsigned char*)mv + e);
            m0 = mm.x; m1 = mm.y; m2 = mm.z; m3 = mm.w;
        } else {
            int4 mm = ((const int4*)mv)[e >> 2];   // int32 or float32 words: !=0 is "keep"
            m0 = mm.x; m1 = mm.y; m2 = mm.z; m3 = mm.w;
        }
        ushort4 o;
        o.x = m0 ? f2bf(v.x) : (unsigned short)0;
        o.y = m1 ? f2bf(v.y) : (unsigned short)0;
        o.z = m2 ? f2bf(v.z) : (unsigned short)0;
        o.w = m3 ? f2bf(v.w) : (unsigned short)0;
        *(ushort4*)(out + e) = o;
    }
}

// ---------- kernel 3: C = tanh(A[M,K] x W[N,K]^T + bias) ----------
// 128x128 block tile, BK=32, 256 threads = 4 waves in 2x2, each wave 64x64 via
// 4x4 grid of v_mfma_f32_16x16x32_bf16. Layouts per HW-verified guide §3:
//   A-op: lane holds A[m=lane&15][k=(lane>>4)*8 + j]
//   B-op: lane holds B[k=(lane>>4)*8 + j][n=lane&15]  (== Wrow[n][k..k+7])
//   C/D : col=lane&15, row=(lane>>4)*4 + reg
template <typename OutT>
__global__ __launch_bounds__(256)
void gemm_bt_bias_tanh(const unsigned short* __restrict__ A,
                       const unsigned short* __restrict__ W,
                       const float* __restrict__ bias,
                       OutT* __restrict__ out,
                       int M, int N, int K) {
    __shared__ unsigned short As[128 * 32];
    __shared__ unsigned short Bs[128 * 32];

    const int t    = threadIdx.x;
    const int lane = t & 63;
    const int wave = t >> 6;
    const int wrow = (wave >> 1) * 64;
    const int wcol = (wave & 1) * 64;
    const int quad = lane >> 4;
    const int r16  = lane & 15;
    const int bm   = blockIdx.y * 128;
    const int bn   = blockIdx.x * 128;

    f32x4 acc[4][4] = {};

    for (int k0 = 0; k0 < K; k0 += 32) {
#pragma unroll
        for (int l = 0; l < 2; ++l) {
            int idx = t + l * 256;          // 0..511 : 16B chunk id
            int row = idx >> 2;             // 0..127
            int col = (idx & 3) << 3;       // 0,8,16,24
            u16x8 va = *(const u16x8*)(A + (size_t)(bm + row) * K + k0 + col);
            u16x8 vb = *(const u16x8*)(W + (size_t)(bn + row) * K + k0 + col);
            ((u16x8*)As)[idx] = va;
            ((u16x8*)Bs)[idx] = vb;
        }
        __syncthreads();

        u16x8 a[4], b[4];
#pragma unroll
        for (int i = 0; i < 4; ++i)
            a[i] = ((const u16x8*)As)[(wrow + i * 16 + r16) * 4 + quad];
#pragma unroll
        for (int j = 0; j < 4; ++j)
            b[j] = ((const u16x8*)Bs)[(wcol + j * 16 + r16) * 4 + quad];
#pragma unroll
        for (int i = 0; i < 4; ++i)
#pragma unroll
            for (int j = 0; j < 4; ++j)
                acc[i][j] = __builtin_amdgcn_mfma_f32_16x16x32_bf16(
                    __builtin_bit_cast(bf16x8f, a[i]),
                    __builtin_bit_cast(bf16x8f, b[j]),
                    acc[i][j], 0, 0, 0);
        __syncthreads();
    }

#pragma unroll
    for (int j = 0; j < 4; ++j) {
        int gn = bn + wcol + j * 16 + r16;
        float bv = bias[gn];
#pragma unroll
        for (int i = 0; i < 4; ++i) {
            int gm0 = bm + wrow + i * 16 + quad * 4;
#pragma unroll
            for (int r = 0; r < 4; ++r) {
                float v = tanhf(acc[i][j][r] + bv);
                if constexpr (sizeof(OutT) == 2)
                    out[(size_t)(gm0 + r) * N + gn] = (OutT)f2bf(v);
                else
                    out[(size_t)(gm0 + r) * N + gn] = (OutT)v;
            }
        }
    }
}

// ---------- kernel 4: fused conv1d(k2,s2)+tanh twice ----------
__global__ __launch_bounds__(256)
void conv_fuse(const float* __restrict__ c, float* __restrict__ out,
               const float* __restrict__ w1, const float* __restrict__ b1,
               const float* __restrict__ w2, const float* __restrict__ b2, int n) {
    int i = blockIdx.x * blockDim.x + threadIdx.x;
    if (i >= n) return;
    float w10 = w1[0], w11 = w1[1], bb1 = b1[0];
    float w20 = w2[0], w21 = w2[1], bb2 = b2[0];
    float4 v = *(const float4*)(c + (size_t)i * 4);
    float y10 = tanhf(v.x * w10 + v.y * w11 + bb1);
    float y11 = tanhf(v.z * w10 + v.w * w11 + bb1);
    out[i] = tanhf(y10 * w20 + y11 * w21 + bb2);
}

// ---------- launch ----------
extern "C" void kernel_launch(void* const* d_in, const int* in_sizes, int n_in,
                              void* d_out, int out_size, void* d_ws, size_t ws_size,
                              hipStream_t stream) {
    constexpr int B   = 16384;
    constexpr int IN  = 4096;
    constexpr int HID = 2048;
    constexpr int CNV = 1024;

    const float* x       = (const float*)d_in[0];
    const void*  mask_ih = d_in[1];
    const void*  mask_hc = d_in[2];
    const float* w_ih    = (const float*)d_in[3];
    const float* b_ih    = (const float*)d_in[4];
    const float* w_hc    = (const float*)d_in[5];
    const float* b_hc    = (const float*)d_in[6];
    const float* w_c1    = (const float*)d_in[7];
    const float* b_c1    = (const float*)d_in[8];
    const float* w_c2    = (const float*)d_in[9];
    const float* b_c2    = (const float*)d_in[10];
    float* out = (float*)d_out;

    // workspace layout (bytes)
    char* ws = (char*)d_ws;
    unsigned short* Xb  = (unsigned short*)(ws);                    // B*IN  bf16 = 134,217,728
    unsigned short* Wih = (unsigned short*)(ws + 134217728);        // HID*IN bf16 = 16,777,216
    unsigned short* Whc = (unsigned short*)(ws + 150994944);        // CNV*HID bf16 = 4,194,304
    unsigned short* Hb  = (unsigned short*)(ws + 155189248);        // B*HID bf16 = 67,108,864
    float*          Cf  = (float*)(ws + 222298112);                 // B*CNV fp32 = 67,108,864
    int*            flag = (int*)(ws + 289406976);                  // 4 bytes

    detect_mask<<<1, 256, 0, stream>>>((const unsigned char*)mask_ih, flag);

    cast_f32_bf16<<<4096, 256, 0, stream>>>(x, Xb, B * IN);
    mask_cast<<<1024, 256, 0, stream>>>(w_ih, mask_ih, flag, Wih, HID * IN);
    mask_cast<<<256, 256, 0, stream>>>(w_hc, mask_hc, flag, Whc, CNV * HID);

    dim3 g1(HID / 128, B / 128);   // (16, 128)
    gemm_bt_bias_tanh<unsigned short><<<g1, 256, 0, stream>>>(Xb, Wih, b_ih, Hb, B, HID, IN);

    dim3 g2(CNV / 128, B / 128);   // (8, 128)
    gemm_bt_bias_tanh<float><<<g2, 256, 0, stream>>>(Hb, Whc, b_hc, Cf, B, CNV, HID);

    conv_fuse<<<(B * (CNV / 4) + 255) / 256, 256, 0, stream>>>(
        Cf, out, w_c1, b_c1, w_c2, b_c2, B * (CNV / 4));
}

// Round 3
// 967.002 us; speedup vs baseline: 1.0528x; 1.0528x over previous
//
#include <hip/hip_runtime.h>
#include <cstdint>
#include <cstddef>

// ---------- types ----------
typedef __bf16  bf16x8f __attribute__((ext_vector_type(8)));      // MFMA A/B operand (4 VGPRs)
typedef unsigned short u16x8 __attribute__((ext_vector_type(8))); // storage view of 8 bf16
typedef float   f32x4  __attribute__((ext_vector_type(4)));       // MFMA C/D operand

__device__ __forceinline__ float bf2f(unsigned short s) {
    union { uint32_t u; float f; } c; c.u = ((uint32_t)s) << 16; return c.f;
}
__device__ __forceinline__ unsigned short f2bf(float f) {
    union { float f; uint32_t u; } c; c.f = f;
    uint32_t u = c.u;
    return (unsigned short)((u + 0x7fffu + ((u >> 16) & 1u)) >> 16);  // RNE
}

// async 16B global -> LDS (DMA, no VGPR round-trip). C-style casts perform
// the addrspacecast (CK-style; reinterpret_cast across AS is ill-formed).
__device__ __forceinline__ void load16_lds(const unsigned short* g, unsigned short* l) {
    __builtin_amdgcn_global_load_lds(
        (const __attribute__((address_space(1))) unsigned int*)g,
        (__attribute__((address_space(3))) unsigned int*)l,
        16, 0, 0);
}

// ---------- kernel 0: detect mask storage layout ----------
// flag=1 -> uint8 (numpy bool) layout; flag=0 -> 32-bit word layout
// (int32 or float32; both handled by word!=0 truthiness).
__global__ __launch_bounds__(256)
void detect_mask(const unsigned char* __restrict__ m, int* __restrict__ flag) {
    __shared__ int s_gt1, s_off;
    if (threadIdx.x == 0) { s_gt1 = 0; s_off = 0; }
    __syncthreads();
    int gt1 = 0, off = 0;
    for (int k = threadIdx.x; k < 4096; k += 256) {
        unsigned char b = m[k];
        if (b > 1) gt1 = 1;
        if ((k & 3) && b) off = 1;
    }
    if (gt1) atomicOr(&s_gt1, 1);
    if (off) atomicOr(&s_off, 1);
    __syncthreads();
    if (threadIdx.x == 0) *flag = (!s_gt1 && s_off) ? 1 : 0;
}

// ---------- kernel 1: cast x fp32 -> bf16 ----------
__global__ __launch_bounds__(256)
void cast_f32_bf16(const float* __restrict__ in, unsigned short* __restrict__ out, int n) {
    int tid = blockIdx.x * blockDim.x + threadIdx.x;
    int stride = gridDim.x * blockDim.x;
    for (int e = tid * 4; e < n; e += stride * 4) {
        float4 v = *(const float4*)(in + e);
        ushort4 o;
        o.x = f2bf(v.x); o.y = f2bf(v.y); o.z = f2bf(v.z); o.w = f2bf(v.w);
        *(ushort4*)(out + e) = o;
    }
}

// ---------- kernel 2: masked weight -> bf16 ----------
__global__ __launch_bounds__(256)
void mask_cast(const float* __restrict__ w, const void* __restrict__ mv,
               const int* __restrict__ flag, unsigned short* __restrict__ out, int n) {
    const bool u8 = (*flag != 0);   // uniform branch
    int tid = blockIdx.x * blockDim.x + threadIdx.x;
    int stride = gridDim.x * blockDim.x;
    for (int e = tid * 4; e < n; e += stride * 4) {
        float4 v = *(const float4*)(w + e);
        int m0, m1, m2, m3;
        if (u8) {
            uchar4 mm = *(const uchar4*)((const unsigned char*)mv + e);
            m0 = mm.x; m1 = mm.y; m2 = mm.z; m3 = mm.w;
        } else {
            int4 mm = ((const int4*)mv)[e >> 2];
            m0 = mm.x; m1 = mm.y; m2 = mm.z; m3 = mm.w;
        }
        ushort4 o;
        o.x = m0 ? f2bf(v.x) : (unsigned short)0;
        o.y = m1 ? f2bf(v.y) : (unsigned short)0;
        o.z = m2 ? f2bf(v.z) : (unsigned short)0;
        o.w = m3 ? f2bf(v.w) : (unsigned short)0;
        *(ushort4*)(out + e) = o;
    }
}

// ---------- kernel 3: C = tanh(A[M,K] x W[N,K]^T + bias) ----------
// 128x128 tile, BK=32, 4 waves (2x2), 4x4 mfma_f32_16x16x32_bf16 per wave.
// Staging via global_load_lds (LDS order forced to lane order: chunk idx =
// tid + l*256). XOR swizzle: global chunk (row,cc) lands at LDS chunk
// row*4 + (cc ^ ((row>>1)&3)) -> fragment-read phases hit all 8 bank windows
// (2 lanes each) instead of 2 windows (8 lanes) -> conflict-free minimum.
template <typename OutT>
__global__ __launch_bounds__(256)
void gemm_bt_bias_tanh(const unsigned short* __restrict__ A,
                       const unsigned short* __restrict__ W,
                       const float* __restrict__ bias,
                       OutT* __restrict__ out,
                       int M, int N, int K) {
    __shared__ unsigned short As[128 * 32];
    __shared__ unsigned short Bs[128 * 32];

    const int t    = threadIdx.x;
    const int lane = t & 63;
    const int wave = t >> 6;
    const int wrow = (wave >> 1) * 64;
    const int wcol = (wave & 1) * 64;
    const int quad = lane >> 4;
    const int r16  = lane & 15;
    const int swz  = (r16 >> 1) & 3;       // row = 16m + r16 -> (row>>1)&3 == (r16>>1)&3
    const int bm   = blockIdx.y * 128;
    const int bn   = blockIdx.x * 128;

    // staging coordinates for this thread (fixed across K-loop)
    const int c0   = t;            // LDS chunk for l=0
    const int c1   = t + 256;      // LDS chunk for l=1
    const int row0 = c0 >> 2, row1 = c1 >> 2;
    const int cc0  = (c0 & 3) ^ ((row0 >> 1) & 3);
    const int cc1  = (c1 & 3) ^ ((row1 >> 1) & 3);
    const unsigned short* ga0 = A + (size_t)(bm + row0) * K + (cc0 << 3);
    const unsigned short* ga1 = A + (size_t)(bm + row1) * K + (cc1 << 3);
    const unsigned short* gb0 = W + (size_t)(bn + row0) * K + (cc0 << 3);
    const unsigned short* gb1 = W + (size_t)(bn + row1) * K + (cc1 << 3);

    f32x4 acc[4][4] = {};

    for (int k0 = 0; k0 < K; k0 += 32) {
        load16_lds(ga0 + k0, As + c0 * 8);
        load16_lds(ga1 + k0, As + c1 * 8);
        load16_lds(gb0 + k0, Bs + c0 * 8);
        load16_lds(gb1 + k0, Bs + c1 * 8);
        __syncthreads();

        u16x8 a[4], b[4];
#pragma unroll
        for (int i = 0; i < 4; ++i) {
            int row = wrow + i * 16 + r16;
            a[i] = ((const u16x8*)As)[row * 4 + (quad ^ swz)];
        }
#pragma unroll
        for (int j = 0; j < 4; ++j) {
            int row = wcol + j * 16 + r16;
            b[j] = ((const u16x8*)Bs)[row * 4 + (quad ^ swz)];
        }
#pragma unroll
        for (int i = 0; i < 4; ++i)
#pragma unroll
            for (int j = 0; j < 4; ++j)
                acc[i][j] = __builtin_amdgcn_mfma_f32_16x16x32_bf16(
                    __builtin_bit_cast(bf16x8f, a[i]),
                    __builtin_bit_cast(bf16x8f, b[j]),
                    acc[i][j], 0, 0, 0);
        __syncthreads();
    }

#pragma unroll
    for (int j = 0; j < 4; ++j) {
        int gn = bn + wcol + j * 16 + r16;
        float bv = bias[gn];
#pragma unroll
        for (int i = 0; i < 4; ++i) {
            int gm0 = bm + wrow + i * 16 + quad * 4;
#pragma unroll
            for (int r = 0; r < 4; ++r) {
                float v = tanhf(acc[i][j][r] + bv);
                if constexpr (sizeof(OutT) == 2)
                    out[(size_t)(gm0 + r) * N + gn] = (OutT)f2bf(v);
                else
                    out[(size_t)(gm0 + r) * N + gn] = (OutT)v;
            }
        }
    }
}

// ---------- kernel 4: fused conv1d(k2,s2)+tanh twice ----------
__global__ __launch_bounds__(256)
void conv_fuse(const float* __restrict__ c, float* __restrict__ out,
               const float* __restrict__ w1, const float* __restrict__ b1,
               const float* __restrict__ w2, const float* __restrict__ b2, int n) {
    int i = blockIdx.x * blockDim.x + threadIdx.x;
    if (i >= n) return;
    float w10 = w1[0], w11 = w1[1], bb1 = b1[0];
    float w20 = w2[0], w21 = w2[1], bb2 = b2[0];
    float4 v = *(const float4*)(c + (size_t)i * 4);
    float y10 = tanhf(v.x * w10 + v.y * w11 + bb1);
    float y11 = tanhf(v.z * w10 + v.w * w11 + bb1);
    out[i] = tanhf(y10 * w20 + y11 * w21 + bb2);
}

// ---------- launch ----------
extern "C" void kernel_launch(void* const* d_in, const int* in_sizes, int n_in,
                              void* d_out, int out_size, void* d_ws, size_t ws_size,
                              hipStream_t stream) {
    constexpr int B   = 16384;
    constexpr int IN  = 4096;
    constexpr int HID = 2048;
    constexpr int CNV = 1024;

    const float* x       = (const float*)d_in[0];
    const void*  mask_ih = d_in[1];
    const void*  mask_hc = d_in[2];
    const float* w_ih    = (const float*)d_in[3];
    const float* b_ih    = (const float*)d_in[4];
    const float* w_hc    = (const float*)d_in[5];
    const float* b_hc    = (const float*)d_in[6];
    const float* w_c1    = (const float*)d_in[7];
    const float* b_c1    = (const float*)d_in[8];
    const float* w_c2    = (const float*)d_in[9];
    const float* b_c2    = (const float*)d_in[10];
    float* out = (float*)d_out;

    // workspace layout (bytes)
    char* ws = (char*)d_ws;
    unsigned short* Xb  = (unsigned short*)(ws);                    // B*IN  bf16 = 134,217,728
    unsigned short* Wih = (unsigned short*)(ws + 134217728);        // HID*IN bf16 = 16,777,216
    unsigned short* Whc = (unsigned short*)(ws + 150994944);        // CNV*HID bf16 = 4,194,304
    unsigned short* Hb  = (unsigned short*)(ws + 155189248);        // B*HID bf16 = 67,108,864
    float*          Cf  = (float*)(ws + 222298112);                 // B*CNV fp32 = 67,108,864
    int*            flag = (int*)(ws + 289406976);                  // 4 bytes

    detect_mask<<<1, 256, 0, stream>>>((const unsigned char*)mask_ih, flag);

    cast_f32_bf16<<<4096, 256, 0, stream>>>(x, Xb, B * IN);
    mask_cast<<<1024, 256, 0, stream>>>(w_ih, mask_ih, flag, Wih, HID * IN);
    mask_cast<<<256, 256, 0, stream>>>(w_hc, mask_hc, flag, Whc, CNV * HID);

    dim3 g1(HID / 128, B / 128);   // (16, 128)
    gemm_bt_bias_tanh<unsigned short><<<g1, 256, 0, stream>>>(Xb, Wih, b_ih, Hb, B, HID, IN);

    dim3 g2(CNV / 128, B / 128);   // (8, 128)
    gemm_bt_bias_tanh<float><<<g2, 256, 0, stream>>>(Hb, Whc, b_hc, Cf, B, CNV, HID);

    conv_fuse<<<(B * (CNV / 4) + 255) / 256, 256, 0, stream>>>(
        Cf, out, w_c1, b_c1, w_c2, b_c2, B * (CNV / 4));
}

// Round 4
// 913.459 us; speedup vs baseline: 1.1146x; 1.0586x over previous
//
#include <hip/hip_runtime.h>
#include <cstdint>
#include <cstddef>

// ---------- types ----------
typedef __bf16  bf16x8f __attribute__((ext_vector_type(8)));      // MFMA A/B operand (4 VGPRs)
typedef unsigned short u16x8 __attribute__((ext_vector_type(8))); // storage view of 8 bf16
typedef float   f32x16 __attribute__((ext_vector_type(16)));      // MFMA 32x32 C/D operand

__device__ __forceinline__ unsigned short f2bf(float f) {
    union { float f; uint32_t u; } c; c.f = f;
    uint32_t u = c.u;
    return (unsigned short)((u + 0x7fffu + ((u >> 16) & 1u)) >> 16);  // RNE
}

// tanh(x) = 1 - 2/(e^{2x}+1); exact at +/-inf, ~1e-6 abs err (v_exp/v_rcp 1ulp)
__device__ __forceinline__ float fast_tanh(float x) {
    float e = __builtin_exp2f(2.885390081777927f * x);   // e^{2x}
    return 1.0f - 2.0f * __builtin_amdgcn_rcpf(e + 1.0f);
}

// async 16B global -> LDS (DMA, no VGPR round-trip)
__device__ __forceinline__ void load16_lds(const void* g, unsigned short* l) {
    __builtin_amdgcn_global_load_lds(
        (const __attribute__((address_space(1))) unsigned int*)g,
        (__attribute__((address_space(3))) unsigned int*)l,
        16, 0, 0);
}

// ---------- kernel 0: detect mask storage layout ----------
// flag=1 -> uint8 (numpy bool); flag=0 -> 32-bit words (int32/float32, !=0 == keep)
__global__ __launch_bounds__(256)
void detect_mask(const unsigned char* __restrict__ m, int* __restrict__ flag) {
    __shared__ int s_gt1, s_off;
    if (threadIdx.x == 0) { s_gt1 = 0; s_off = 0; }
    __syncthreads();
    int gt1 = 0, off = 0;
    for (int k = threadIdx.x; k < 4096; k += 256) {
        unsigned char b = m[k];
        if (b > 1) gt1 = 1;
        if ((k & 3) && b) off = 1;
    }
    if (gt1) atomicOr(&s_gt1, 1);
    if (off) atomicOr(&s_off, 1);
    __syncthreads();
    if (threadIdx.x == 0) *flag = (!s_gt1 && s_off) ? 1 : 0;
}

// ---------- kernel 1: cast x fp32 -> bf16 ----------
__global__ __launch_bounds__(256)
void cast_f32_bf16(const float* __restrict__ in, unsigned short* __restrict__ out, int n) {
    int tid = blockIdx.x * blockDim.x + threadIdx.x;
    int stride = gridDim.x * blockDim.x;
    for (int e = tid * 4; e < n; e += stride * 4) {
        float4 v = *(const float4*)(in + e);
        ushort4 o;
        o.x = f2bf(v.x); o.y = f2bf(v.y); o.z = f2bf(v.z); o.w = f2bf(v.w);
        *(ushort4*)(out + e) = o;
    }
}

// ---------- kernel 2: masked weight -> bf16 ----------
__global__ __launch_bounds__(256)
void mask_cast(const float* __restrict__ w, const void* __restrict__ mv,
               const int* __restrict__ flag, unsigned short* __restrict__ out, int n) {
    const bool u8 = (*flag != 0);   // uniform branch
    int tid = blockIdx.x * blockDim.x + threadIdx.x;
    int stride = gridDim.x * blockDim.x;
    for (int e = tid * 4; e < n; e += stride * 4) {
        float4 v = *(const float4*)(w + e);
        int m0, m1, m2, m3;
        if (u8) {
            uchar4 mm = *(const uchar4*)((const unsigned char*)mv + e);
            m0 = mm.x; m1 = mm.y; m2 = mm.z; m3 = mm.w;
        } else {
            int4 mm = ((const int4*)mv)[e >> 2];
            m0 = mm.x; m1 = mm.y; m2 = mm.z; m3 = mm.w;
        }
        ushort4 o;
        o.x = m0 ? f2bf(v.x) : (unsigned short)0;
        o.y = m1 ? f2bf(v.y) : (unsigned short)0;
        o.z = m2 ? f2bf(v.z) : (unsigned short)0;
        o.w = m3 ? f2bf(v.w) : (unsigned short)0;
        *(ushort4*)(out + e) = o;
    }
}

// ---------- GEMM: C = tanh(A[M,K] x W[N,K]^T + bias), 32x32x16 MFMA ----------
// 128x128 tile, BK=32, 4 waves (2x2), each wave 64x64 = 2x2 of 32x32.
// Layouts (HW-verified, guide §3):
//   A-op: lane holds A[m=lane&31][k=(lane>>5)*8 + j] (+16 per k-step s)
//   B-op: lane holds B[k][n=lane&31]  == Wrow[n][k..k+7]
//   C/D : col=lane&31, row=(reg&3)+8*(reg>>2)+4*(lane>>5)
// Staging: global_load_lds lane-order; XOR swizzle (cc ^ (row>>1)&3) makes
// fragment ds_read_b128 conflict-free (verified: conflicts 0 in r3).
// XCD swizzle: 1-D grid, blocks sharing an A-row have ids == same (mod 8).
// FUSE: conv1d(k2,s2)+tanh twice folded into epilogue via shfl_xor (cols are
// lane-adjacent in C/D layout); out is [M, N/4] fp32.
template <typename OutT, bool FUSE>
__global__ __launch_bounds__(256)
void gemm32(const unsigned short* __restrict__ A,
            const unsigned short* __restrict__ W,
            const float* __restrict__ bias,
            OutT* __restrict__ out,
            const float* __restrict__ w1, const float* __restrict__ b1,
            const float* __restrict__ w2, const float* __restrict__ b2,
            int M, int N, int K, int lbx) {
    __shared__ unsigned short As[128 * 32];
    __shared__ unsigned short Bs[128 * 32];

    const int t    = threadIdx.x;
    const int lane = t & 63;
    const int wave = t >> 6;
    const int wrow = (wave >> 1) * 64;
    const int wcol = (wave & 1) * 64;
    const int l31  = lane & 31;
    const int lh   = lane >> 5;
    const int swz  = (l31 >> 1) & 3;

    const int id = blockIdx.x;
    const int bx = (id >> 3) & ((1 << lbx) - 1);
    const int by = (id & 7) | ((id >> (3 + lbx)) << 3);
    const int bm = by * 128;
    const int bn = bx * 128;

    // staging coords: LDS chunk c holds global chunk (row=c>>2, (c&3)^((row>>1)&3))
    const int c0 = t, c1 = t + 256;
    const int row0 = c0 >> 2, row1 = c1 >> 2;
    const int cc0 = (c0 & 3) ^ ((row0 >> 1) & 3);
    const int cc1 = (c1 & 3) ^ ((row1 >> 1) & 3);
    // divergent, loop-invariant byte offsets; uniform base advances by k0
    const uint32_t va0 = (uint32_t)(row0 * K + cc0 * 8) * 2;
    const uint32_t va1 = (uint32_t)(row1 * K + cc1 * 8) * 2;
    const char* Au = (const char*)(A + (size_t)bm * K);
    const char* Wu = (const char*)(W + (size_t)bn * K);

    f32x16 acc[2][2] = {};

    for (int k0 = 0; k0 < K; k0 += 32) {
        const char* Ak = Au + (size_t)(k0 * 2);
        const char* Wk = Wu + (size_t)(k0 * 2);
        load16_lds(Ak + va0, As + c0 * 8);
        load16_lds(Ak + va1, As + c1 * 8);
        load16_lds(Wk + va0, Bs + c0 * 8);
        load16_lds(Wk + va1, Bs + c1 * 8);
        __syncthreads();

        u16x8 a[2][2], b[2][2];   // [tile][k-step]
#pragma unroll
        for (int s = 0; s < 2; ++s) {
            int q = (s * 2 + lh) ^ swz;
#pragma unroll
            for (int i = 0; i < 2; ++i) {
                a[i][s] = ((const u16x8*)As)[(wrow + i * 32 + l31) * 4 + q];
                b[i][s] = ((const u16x8*)Bs)[(wcol + i * 32 + l31) * 4 + q];
            }
        }
#pragma unroll
        for (int s = 0; s < 2; ++s)
#pragma unroll
            for (int i = 0; i < 2; ++i)
#pragma unroll
                for (int j = 0; j < 2; ++j)
                    acc[i][j] = __builtin_amdgcn_mfma_f32_32x32x16_bf16(
                        __builtin_bit_cast(bf16x8f, a[i][s]),
                        __builtin_bit_cast(bf16x8f, b[j][s]),
                        acc[i][j], 0, 0, 0);
        __syncthreads();
    }

    // ---- epilogue ----
    float w10 = 0, w11 = 0, bb1 = 0, w20 = 0, w21 = 0, bb2 = 0;
    if constexpr (FUSE) {
        w10 = w1[0]; w11 = w1[1]; bb1 = b1[0];
        w20 = w2[0]; w21 = w2[1]; bb2 = b2[0];
    }
#pragma unroll
    for (int j = 0; j < 2; ++j) {
        const int gn = bn + wcol + j * 32 + l31;
        const float bv = bias[gn];
#pragma unroll
        for (int i = 0; i < 2; ++i) {
#pragma unroll
            for (int reg = 0; reg < 16; ++reg) {
                const int gm = bm + wrow + i * 32 + (reg & 3) + 8 * (reg >> 2) + 4 * lh;
                float c = fast_tanh(acc[i][j][reg] + bv);
                if constexpr (FUSE) {
                    float c1 = __shfl_xor(c, 1);
                    float c2 = __shfl_xor(c, 2);
                    float c3 = __shfl_xor(c, 3);
                    float y10 = fast_tanh(w10 * c  + w11 * c1 + bb1);
                    float y11 = fast_tanh(w10 * c2 + w11 * c3 + bb1);
                    float y   = fast_tanh(w20 * y10 + w21 * y11 + bb2);
                    if ((lane & 3) == 0)
                        out[(size_t)gm * (N >> 2) + (gn >> 2)] = (OutT)y;
                } else {
                    out[(size_t)gm * N + gn] = (OutT)f2bf(c);
                }
            }
        }
    }
}

// ---------- launch ----------
extern "C" void kernel_launch(void* const* d_in, const int* in_sizes, int n_in,
                              void* d_out, int out_size, void* d_ws, size_t ws_size,
                              hipStream_t stream) {
    constexpr int B   = 16384;
    constexpr int IN  = 4096;
    constexpr int HID = 2048;
    constexpr int CNV = 1024;

    const float* x       = (const float*)d_in[0];
    const void*  mask_ih = d_in[1];
    const void*  mask_hc = d_in[2];
    const float* w_ih    = (const float*)d_in[3];
    const float* b_ih    = (const float*)d_in[4];
    const float* w_hc    = (const float*)d_in[5];
    const float* b_hc    = (const float*)d_in[6];
    const float* w_c1    = (const float*)d_in[7];
    const float* b_c1    = (const float*)d_in[8];
    const float* w_c2    = (const float*)d_in[9];
    const float* b_c2    = (const float*)d_in[10];
    float* out = (float*)d_out;

    // workspace layout (bytes)
    char* ws = (char*)d_ws;
    unsigned short* Xb  = (unsigned short*)(ws);                    // B*IN  bf16 = 134,217,728
    unsigned short* Wih = (unsigned short*)(ws + 134217728);        // HID*IN bf16 = 16,777,216
    unsigned short* Whc = (unsigned short*)(ws + 150994944);        // CNV*HID bf16 = 4,194,304
    unsigned short* Hb  = (unsigned short*)(ws + 155189248);        // B*HID bf16 = 67,108,864
    int*            flag = (int*)(ws + 222298112);                  // 4 bytes

    detect_mask<<<1, 256, 0, stream>>>((const unsigned char*)mask_ih, flag);

    cast_f32_bf16<<<4096, 256, 0, stream>>>(x, Xb, B * IN);
    mask_cast<<<1024, 256, 0, stream>>>(w_ih, mask_ih, flag, Wih, HID * IN);
    mask_cast<<<256, 256, 0, stream>>>(w_hc, mask_hc, flag, Whc, CNV * HID);

    // GEMM1: [16384,4096] x [2048,4096]^T -> bf16 h ; grid 16x128 -> 2048 blocks, lbx=4
    gemm32<unsigned short, false><<<2048, 256, 0, stream>>>(
        Xb, Wih, b_ih, Hb, nullptr, nullptr, nullptr, nullptr, B, HID, IN, 4);

    // GEMM2 + fused double conv: [16384,2048] x [1024,2048]^T -> fp32 y [16384,256]
    // grid 8x128 -> 1024 blocks, lbx=3
    gemm32<float, true><<<1024, 256, 0, stream>>>(
        Hb, Whc, b_hc, out, w_c1, b_c1, w_c2, b_c2, B, CNV, HID, 3);
}